// Round 2
// baseline (305.151 us; speedup 1.0000x reference)
//
#include <hip/hip_runtime.h>
#include <math.h>

// Elastic transform: [32,256,1024,3] fp32, 3x3 control grid displacement.
//   k_disp      : dense dy/dx fields [256,1024] from 3x3 control points
//   k_prefilt_h : cubic spline prefilter along H (37-tap mirror FIR)
//   k_prefilt_w : same along W, in place, row staged in LDS
//   k_sample    : 4x4 cubic gather; coef region staged per 32x32 tile in LDS

#define H_ 256
#define W_ 1024
#define B_ 32
#define C_ 3
#define RAD 18               // |z|^18 ~ 5e-11, z = sqrt(3)-2
#define ROWF 3072            // W_*C_ floats per (b,h) row
#define LDSF 12288           // 48 KiB float capacity for the sample tile

__device__ __forceinline__ float b3f(float t) {
    float a = fabsf(t);
    if (a < 1.0f) return (4.0f - 6.0f * a * a + 3.0f * a * a * a) * (1.0f / 6.0f);
    if (a < 2.0f) { float s = 2.0f - a; return s * s * s * (1.0f / 6.0f); }
    return 0.0f;
}

// branch-free cubic B-spline weights for fractional offset f in [0,1):
// w[k] = b3f(f - (k-1)), k = 0..3
__device__ __forceinline__ void cubw(float f, float* w) {
    float f2 = f * f, f3 = f2 * f;
    float om = 1.0f - f;
    w[0] = om * om * om * (1.0f / 6.0f);
    w[1] = (3.0f * f3 - 6.0f * f2 + 4.0f) * (1.0f / 6.0f);
    w[2] = (-3.0f * f3 + 3.0f * f2 + 3.0f * f + 1.0f) * (1.0f / 6.0f);
    w[3] = f3 * (1.0f / 6.0f);
}

__device__ __forceinline__ float clamp01(float v) {
    return fminf(fmaxf(v, 0.0f), 1.0f);
}

__device__ __forceinline__ void basis3(int i, int n, float& w0, float& w1, float& w2) {
    float u = (float)i * 2.0f / (float)(n - 1);
    int base = (int)floorf(u);
    w0 = w1 = w2 = 0.0f;
#pragma unroll
    for (int k = -1; k < 3; ++k) {
        int id = base + k;
        float bw = b3f(u - (float)id);
        int j = id < 0 ? -id : id;
        j &= 3;
        if (j == 3) j = 1;
        if (j == 0) w0 += bw; else if (j == 1) w1 += bw; else w2 += bw;
    }
}

// ---------------- kernel 0: displacement fields ----------------
__global__ __launch_bounds__(256) void k_disp(const float* __restrict__ disp,
                                              float* __restrict__ dyp,
                                              float* __restrict__ dxp) {
    int idx = blockIdx.x * 256 + threadIdx.x;
    int h = idx >> 10, w = idx & 1023;

    const float A[3][3] = {{1.75f, -1.0f, 0.25f},
                           {-0.5f,  2.0f, -0.5f},
                           {0.25f, -1.0f, 1.75f}};
    float Ty[3][3], Tx[3][3];
#pragma unroll
    for (int i = 0; i < 3; ++i)
#pragma unroll
        for (int j = 0; j < 3; ++j) {
            float ty = 0.f, tx = 0.f;
#pragma unroll
            for (int k = 0; k < 3; ++k) {
                ty += A[i][k] * (5.0f * disp[k * 3 + j]);
                tx += A[i][k] * (5.0f * disp[9 + k * 3 + j]);
            }
            Ty[i][j] = ty; Tx[i][j] = tx;
        }
    float Cy[3][3], Cx[3][3];
#pragma unroll
    for (int i = 0; i < 3; ++i)
#pragma unroll
        for (int j = 0; j < 3; ++j) {
            float ty = 0.f, tx = 0.f;
#pragma unroll
            for (int k = 0; k < 3; ++k) {
                ty += Ty[i][k] * A[j][k];
                tx += Tx[i][k] * A[j][k];
            }
            Cy[i][j] = ty; Cx[i][j] = tx;
        }

    float rh0, rh1, rh2, rw0, rw1, rw2;
    basis3(h, H_, rh0, rh1, rh2);
    basis3(w, W_, rw0, rw1, rw2);
    float rh[3] = {rh0, rh1, rh2}, rw[3] = {rw0, rw1, rw2};

    float dy = 0.f, dx = 0.f;
#pragma unroll
    for (int i = 0; i < 3; ++i)
#pragma unroll
        for (int j = 0; j < 3; ++j) {
            dy += rh[i] * Cy[i][j] * rw[j];
            dx += rh[i] * Cx[i][j] * rw[j];
        }
    dyp[idx] = dy;
    dxp[idx] = dx;
}

// ---------------- kernel 1: prefilter along H ----------------
__global__ __launch_bounds__(256) void k_prefilt_h(const float* __restrict__ x,
                                                   float* __restrict__ coef) {
    __shared__ float tile[H_ * 64];   // 64 KiB
    const int chunk = blockIdx.x;     // 0..47
    const int b = blockIdx.y;
    const int tid = threadIdx.x;

    const float* src = x + (size_t)b * H_ * ROWF + chunk * 64;
#pragma unroll
    for (int it = 0; it < 16; ++it) {
        int idx = tid + it * 256;
        int r = idx >> 4, seg = idx & 15;
        *(float4*)(tile + r * 64 + seg * 4) =
            *(const float4*)(src + (size_t)r * ROWF + seg * 4);
    }
    __syncthreads();

    float g[RAD + 1];
    g[0] = 1.7320508075688773f;
#pragma unroll
    for (int k = 1; k <= RAD; ++k) g[k] = g[k - 1] * (-0.26794919243112270647f);

    const int cg = tid & 15;
    const int prow = tid >> 4;
    const int p0 = prow * 16;

    float acc[16][4];
#pragma unroll
    for (int j = 0; j < 16; ++j) {
        acc[j][0] = 0.f; acc[j][1] = 0.f; acc[j][2] = 0.f; acc[j][3] = 0.f;
    }

#pragma unroll
    for (int r = 0; r < 16 + 2 * RAD; ++r) {
        int hh = p0 - RAD + r;
        int m1 = hh < 0 ? -hh : hh;
        int m2 = 2 * (H_ - 1) - hh;
        int mp = m1 < m2 ? m1 : m2;
        float4 v = *(const float4*)(tile + mp * 64 + cg * 4);
#pragma unroll
        for (int j = 0; j < 16; ++j) {
            const int d = r - RAD - j;
            if (d >= -RAD && d <= RAD) {
                const float wgt = g[d < 0 ? -d : d];
                acc[j][0] += wgt * v.x;
                acc[j][1] += wgt * v.y;
                acc[j][2] += wgt * v.z;
                acc[j][3] += wgt * v.w;
            }
        }
    }

    float* dst = coef + (size_t)b * H_ * ROWF + chunk * 64 + cg * 4;
#pragma unroll
    for (int j = 0; j < 16; ++j) {
        float4 o;
        o.x = acc[j][0]; o.y = acc[j][1]; o.z = acc[j][2]; o.w = acc[j][3];
        *(float4*)(dst + (size_t)(p0 + j) * ROWF) = o;
    }
}

// ---------------- kernel 2: prefilter along W (in place) ----------------
#define PLN 1064
__global__ __launch_bounds__(256) void k_prefilt_w(float* __restrict__ coef) {
    __shared__ float pl[3 * PLN];
    const int bp = blockIdx.x;
    const int t = threadIdx.x;
    float* row = coef + (size_t)bp * ROWF;

    {
        float4 v0 = *(const float4*)(row + 12 * t);
        float4 v1 = *(const float4*)(row + 12 * t + 4);
        float4 v2 = *(const float4*)(row + 12 * t + 8);
        float vals[12] = {v0.x, v0.y, v0.z, v0.w,
                          v1.x, v1.y, v1.z, v1.w,
                          v2.x, v2.y, v2.z, v2.w};
        const int q0 = 4 * t;
#pragma unroll
        for (int e = 0; e < 12; ++e) {
            pl[(e % 3) * PLN + RAD + q0 + e / 3] = vals[e];
        }
    }
    __syncthreads();

    if (t < 108) {
        int c = t / 36, i2 = t % 36;
        float* p = pl + c * PLN;
        if (i2 < 18) p[i2] = p[36 - i2];
        else { int r2 = i2 - 18; p[1042 + r2] = p[1040 - r2]; }
    }
    __syncthreads();

    float g[RAD + 1];
    g[0] = 1.7320508075688773f;
#pragma unroll
    for (int k = 1; k <= RAD; ++k) g[k] = g[k - 1] * (-0.26794919243112270647f);

    float acc[3][4];
#pragma unroll
    for (int c = 0; c < 3; ++c) { acc[c][0] = acc[c][1] = acc[c][2] = acc[c][3] = 0.f; }

#pragma unroll
    for (int c = 0; c < 3; ++c) {
        const float* p = pl + c * PLN + 4 * t;
        float w[40];
#pragma unroll
        for (int i = 0; i < 10; ++i) {
            float4 v = *(const float4*)(p + 4 * i);
            w[4 * i] = v.x; w[4 * i + 1] = v.y; w[4 * i + 2] = v.z; w[4 * i + 3] = v.w;
        }
#pragma unroll
        for (int jq = 0; jq < 4; ++jq) {
#pragma unroll
            for (int k = -RAD; k <= RAD; ++k) {
                acc[c][jq] += g[k < 0 ? -k : k] * w[jq + RAD + k];
            }
        }
    }

    float outv[12];
#pragma unroll
    for (int e = 0; e < 12; ++e) outv[e] = acc[e % 3][e / 3];
    float4 s0, s1, s2;
    s0.x = outv[0]; s0.y = outv[1]; s0.z = outv[2]; s0.w = outv[3];
    s1.x = outv[4]; s1.y = outv[5]; s1.z = outv[6]; s1.w = outv[7];
    s2.x = outv[8]; s2.y = outv[9]; s2.z = outv[10]; s2.w = outv[11];
    *(float4*)(row + 12 * t) = s0;
    *(float4*)(row + 12 * t + 4) = s1;
    *(float4*)(row + 12 * t + 8) = s2;
}

// ---------------- kernel 3: 4x4 cubic gather, LDS-tiled ----------------
// grid (32, 8, 32) = (tile_x, tile_y, batch); 32x32 output tile per block;
// thread t: x = t&31, base row = t>>5, rows += 8 for j=0..3.
__global__ __launch_bounds__(256) void k_sample(const float* __restrict__ coef,
                                                const float* __restrict__ dyp,
                                                const float* __restrict__ dxp,
                                                float* __restrict__ out) {
    __shared__ float lds[LDSF];
    __shared__ int s_ymin, s_ymax, s_xmin, s_xmax;

    const int t = threadIdx.x;
    const int tx = t & 31, ty = t >> 5;
    const int b = blockIdx.z;
    const int w = blockIdx.x * 32 + tx;
    const int h0 = blockIdx.y * 32 + ty;

    if (t == 0) { s_ymin = 1 << 30; s_ymax = -(1 << 30);
                  s_xmin = 1 << 30; s_xmax = -(1 << 30); }
    __syncthreads();

    float cyv[4], cxv[4];
    int lymin = 1 << 30, lymax = -(1 << 30), lxmin = 1 << 30, lxmax = -(1 << 30);
#pragma unroll
    for (int j = 0; j < 4; ++j) {
        int h = h0 + 8 * j;
        int hw = (h << 10) | w;
        float cy = (float)h + dyp[hw];
        float cx = (float)w + dxp[hw];
        cyv[j] = cy; cxv[j] = cx;
        int by = (int)floorf(cy), bx = (int)floorf(cx);
        lymin = min(lymin, by); lymax = max(lymax, by);
        lxmin = min(lxmin, bx); lxmax = max(lxmax, bx);
    }
    atomicMin(&s_ymin, lymin); atomicMax(&s_ymax, lymax);
    atomicMin(&s_xmin, lxmin); atomicMax(&s_xmax, lxmax);
    __syncthreads();

    const int y0 = s_ymin - 1, x0 = s_xmin - 1;
    const int RH = s_ymax + 2 - y0 + 1;
    const int RW = s_xmax + 2 - x0 + 1;
    const int RW3 = RW * 3;
    const float* coefb = coef + (size_t)b * H_ * ROWF;

    if (RH * RW3 <= LDSF) {
        // ---- stage clamped region ----
        const bool xcl = (x0 < 0) || (x0 + RW - 1 > W_ - 1);
        const int total = RH * RW3;
        int i = t;
        int r = i / RW3;
        int cc = i - r * RW3;
        for (; i < total; i += 256) {
            int gy = min(max(y0 + r, 0), H_ - 1);
            float v;
            if (!xcl) {
                v = coefb[(size_t)gy * ROWF + x0 * 3 + cc];
            } else {
                int q = cc / 3, ch = cc - q * 3;
                int gx = min(max(x0 + q, 0), W_ - 1);
                v = coefb[(size_t)gy * ROWF + gx * 3 + ch];
            }
            lds[r * RW3 + cc] = v;
            cc += 256;
            while (cc >= RW3) { cc -= RW3; ++r; }
        }
        __syncthreads();

        // ---- gather from LDS ----
#pragma unroll
        for (int j = 0; j < 4; ++j) {
            float cy = cyv[j], cx = cxv[j];
            float byf = floorf(cy), bxf = floorf(cx);
            int by = (int)byf, bx = (int)bxf;
            float wy[4], wx[4];
            cubw(cy - byf, wy);
            cubw(cx - bxf, wx);

            int rb = by - 1 - y0;
            int cb = (bx - 1 - x0) * 3;
            float a0 = 0.f, a1 = 0.f, a2 = 0.f;
#pragma unroll
            for (int ky = 0; ky < 4; ++ky) {
                const float* p = lds + (rb + ky) * RW3 + cb;
                float wyk = wy[ky];
#pragma unroll
                for (int kx = 0; kx < 4; ++kx) {
                    float wgt = wyk * wx[kx];
                    a0 += wgt * p[kx * 3 + 0];
                    a1 += wgt * p[kx * 3 + 1];
                    a2 += wgt * p[kx * 3 + 2];
                }
            }
            int h = h0 + 8 * j;
            float* o = out + ((size_t)(b * H_ + h) * W_ + w) * 3;
            o[0] = clamp01(a0);
            o[1] = clamp01(a1);
            o[2] = clamp01(a2);
        }
    } else {
        // ---- fallback: direct global gather (region too large) ----
#pragma unroll
        for (int j = 0; j < 4; ++j) {
            float cy = cyv[j], cx = cxv[j];
            float byf = floorf(cy), bxf = floorf(cx);
            int by = (int)byf, bx = (int)bxf;
            float wy[4], wx[4];
            cubw(cy - byf, wy);
            cubw(cx - bxf, wx);

            float a0 = 0.f, a1 = 0.f, a2 = 0.f;
#pragma unroll
            for (int ky = 0; ky < 4; ++ky) {
                int iy = min(max(by + ky - 1, 0), H_ - 1);
                const float* rp = coefb + (size_t)iy * ROWF;
                float wyk = wy[ky];
#pragma unroll
                for (int kx = 0; kx < 4; ++kx) {
                    int ix = min(max(bx + kx - 1, 0), W_ - 1);
                    float wgt = wyk * wx[kx];
                    const float* p = rp + ix * 3;
                    a0 += wgt * p[0];
                    a1 += wgt * p[1];
                    a2 += wgt * p[2];
                }
            }
            int h = h0 + 8 * j;
            float* o = out + ((size_t)(b * H_ + h) * W_ + w) * 3;
            o[0] = clamp01(a0);
            o[1] = clamp01(a1);
            o[2] = clamp01(a2);
        }
    }
}

extern "C" void kernel_launch(void* const* d_in, const int* in_sizes, int n_in,
                              void* d_out, int out_size, void* d_ws, size_t ws_size,
                              hipStream_t stream) {
    const float* x = (const float*)d_in[0];      // [32,256,1024,3]
    const float* disp = (const float*)d_in[1];   // [2,3,3]
    float* out = (float*)d_out;

    char* ws = (char*)d_ws;
    float* coef = (float*)ws;                                  // 96 MiB
    float* dy = (float*)(ws + 100663296ull);                   // 1 MiB
    float* dx = (float*)(ws + 100663296ull + 1048576ull);      // 1 MiB

    k_disp<<<dim3((H_ * W_) / 256), dim3(256), 0, stream>>>(disp, dy, dx);

    dim3 g1(ROWF / 64, B_);
    k_prefilt_h<<<g1, dim3(256), 0, stream>>>(x, coef);

    k_prefilt_w<<<dim3(B_ * H_), dim3(256), 0, stream>>>(coef);

    dim3 g3(W_ / 32, H_ / 32, B_);
    k_sample<<<g3, dim3(256), 0, stream>>>(coef, dy, dx, out);
}

// Round 3
// 198.251 us; speedup vs baseline: 1.5392x; 1.5392x over previous
//
#include <hip/hip_runtime.h>
#include <math.h>

// Elastic transform: [32,256,1024,3] fp32, 3x3 control grid displacement.
//   k_disp      : dense dy/dx fields [256,1024] from 3x3 control points
//   k_prefilt_h : cubic spline prefilter along H (37-tap mirror FIR)
//   k_prefilt_w : same along W, in place, row staged in LDS
//   k_sample    : 4x4 cubic gather; weights/offsets amortized across batch
//                 (displacement field is batch-independent)

#define H_ 256
#define W_ 1024
#define B_ 32
#define C_ 3
#define RAD 18               // |z|^18 ~ 5e-11, z = sqrt(3)-2
#define ROWF 3072            // W_*C_ floats per (b,h) row
#define NBS 2                // batch splits in k_sample (occupancy)

__device__ __forceinline__ float b3f(float t) {
    float a = fabsf(t);
    if (a < 1.0f) return (4.0f - 6.0f * a * a + 3.0f * a * a * a) * (1.0f / 6.0f);
    if (a < 2.0f) { float s = 2.0f - a; return s * s * s * (1.0f / 6.0f); }
    return 0.0f;
}

// branch-free cubic B-spline weights for fractional f in [0,1):
// w[k] = b3f(f - (k-1))
__device__ __forceinline__ void cubw(float f, float* w) {
    float f2 = f * f, f3 = f2 * f;
    float om = 1.0f - f;
    w[0] = om * om * om * (1.0f / 6.0f);
    w[1] = (3.0f * f3 - 6.0f * f2 + 4.0f) * (1.0f / 6.0f);
    w[2] = (-3.0f * f3 + 3.0f * f2 + 3.0f * f + 1.0f) * (1.0f / 6.0f);
    w[3] = f3 * (1.0f / 6.0f);
}

__device__ __forceinline__ float clamp01(float v) {
    return fminf(fmaxf(v, 0.0f), 1.0f);
}

__device__ __forceinline__ void basis3(int i, int n, float& w0, float& w1, float& w2) {
    float u = (float)i * 2.0f / (float)(n - 1);
    int base = (int)floorf(u);
    w0 = w1 = w2 = 0.0f;
#pragma unroll
    for (int k = -1; k < 3; ++k) {
        int id = base + k;
        float bw = b3f(u - (float)id);
        int j = id < 0 ? -id : id;
        j &= 3;
        if (j == 3) j = 1;
        if (j == 0) w0 += bw; else if (j == 1) w1 += bw; else w2 += bw;
    }
}

// ---------------- kernel 0: displacement fields ----------------
__global__ __launch_bounds__(256) void k_disp(const float* __restrict__ disp,
                                              float* __restrict__ dyp,
                                              float* __restrict__ dxp) {
    int idx = blockIdx.x * 256 + threadIdx.x;
    int h = idx >> 10, w = idx & 1023;

    const float A[3][3] = {{1.75f, -1.0f, 0.25f},
                           {-0.5f,  2.0f, -0.5f},
                           {0.25f, -1.0f, 1.75f}};
    float Ty[3][3], Tx[3][3];
#pragma unroll
    for (int i = 0; i < 3; ++i)
#pragma unroll
        for (int j = 0; j < 3; ++j) {
            float ty = 0.f, tx = 0.f;
#pragma unroll
            for (int k = 0; k < 3; ++k) {
                ty += A[i][k] * (5.0f * disp[k * 3 + j]);
                tx += A[i][k] * (5.0f * disp[9 + k * 3 + j]);
            }
            Ty[i][j] = ty; Tx[i][j] = tx;
        }
    float Cy[3][3], Cx[3][3];
#pragma unroll
    for (int i = 0; i < 3; ++i)
#pragma unroll
        for (int j = 0; j < 3; ++j) {
            float ty = 0.f, tx = 0.f;
#pragma unroll
            for (int k = 0; k < 3; ++k) {
                ty += Ty[i][k] * A[j][k];
                tx += Tx[i][k] * A[j][k];
            }
            Cy[i][j] = ty; Cx[i][j] = tx;
        }

    float rh0, rh1, rh2, rw0, rw1, rw2;
    basis3(h, H_, rh0, rh1, rh2);
    basis3(w, W_, rw0, rw1, rw2);
    float rh[3] = {rh0, rh1, rh2}, rw[3] = {rw0, rw1, rw2};

    float dy = 0.f, dx = 0.f;
#pragma unroll
    for (int i = 0; i < 3; ++i)
#pragma unroll
        for (int j = 0; j < 3; ++j) {
            dy += rh[i] * Cy[i][j] * rw[j];
            dx += rh[i] * Cx[i][j] * rw[j];
        }
    dyp[idx] = dy;
    dxp[idx] = dx;
}

// ---------------- kernel 1: prefilter along H ----------------
__global__ __launch_bounds__(256) void k_prefilt_h(const float* __restrict__ x,
                                                   float* __restrict__ coef) {
    __shared__ float tile[H_ * 64];   // 64 KiB
    const int chunk = blockIdx.x;     // 0..47
    const int b = blockIdx.y;
    const int tid = threadIdx.x;

    const float* src = x + (size_t)b * H_ * ROWF + chunk * 64;
#pragma unroll
    for (int it = 0; it < 16; ++it) {
        int idx = tid + it * 256;
        int r = idx >> 4, seg = idx & 15;
        *(float4*)(tile + r * 64 + seg * 4) =
            *(const float4*)(src + (size_t)r * ROWF + seg * 4);
    }
    __syncthreads();

    float g[RAD + 1];
    g[0] = 1.7320508075688773f;
#pragma unroll
    for (int k = 1; k <= RAD; ++k) g[k] = g[k - 1] * (-0.26794919243112270647f);

    const int cg = tid & 15;
    const int prow = tid >> 4;
    const int p0 = prow * 16;

    float acc[16][4];
#pragma unroll
    for (int j = 0; j < 16; ++j) {
        acc[j][0] = 0.f; acc[j][1] = 0.f; acc[j][2] = 0.f; acc[j][3] = 0.f;
    }

#pragma unroll
    for (int r = 0; r < 16 + 2 * RAD; ++r) {
        int hh = p0 - RAD + r;
        int m1 = hh < 0 ? -hh : hh;
        int m2 = 2 * (H_ - 1) - hh;
        int mp = m1 < m2 ? m1 : m2;
        float4 v = *(const float4*)(tile + mp * 64 + cg * 4);
#pragma unroll
        for (int j = 0; j < 16; ++j) {
            const int d = r - RAD - j;
            if (d >= -RAD && d <= RAD) {
                const float wgt = g[d < 0 ? -d : d];
                acc[j][0] += wgt * v.x;
                acc[j][1] += wgt * v.y;
                acc[j][2] += wgt * v.z;
                acc[j][3] += wgt * v.w;
            }
        }
    }

    float* dst = coef + (size_t)b * H_ * ROWF + chunk * 64 + cg * 4;
#pragma unroll
    for (int j = 0; j < 16; ++j) {
        float4 o;
        o.x = acc[j][0]; o.y = acc[j][1]; o.z = acc[j][2]; o.w = acc[j][3];
        *(float4*)(dst + (size_t)(p0 + j) * ROWF) = o;
    }
}

// ---------------- kernel 2: prefilter along W (in place) ----------------
#define PLN 1064
__global__ __launch_bounds__(256) void k_prefilt_w(float* __restrict__ coef) {
    __shared__ float pl[3 * PLN];
    const int bp = blockIdx.x;
    const int t = threadIdx.x;
    float* row = coef + (size_t)bp * ROWF;

    {
        float4 v0 = *(const float4*)(row + 12 * t);
        float4 v1 = *(const float4*)(row + 12 * t + 4);
        float4 v2 = *(const float4*)(row + 12 * t + 8);
        float vals[12] = {v0.x, v0.y, v0.z, v0.w,
                          v1.x, v1.y, v1.z, v1.w,
                          v2.x, v2.y, v2.z, v2.w};
        const int q0 = 4 * t;
#pragma unroll
        for (int e = 0; e < 12; ++e) {
            pl[(e % 3) * PLN + RAD + q0 + e / 3] = vals[e];
        }
    }
    __syncthreads();

    if (t < 108) {
        int c = t / 36, i2 = t % 36;
        float* p = pl + c * PLN;
        if (i2 < 18) p[i2] = p[36 - i2];
        else { int r2 = i2 - 18; p[1042 + r2] = p[1040 - r2]; }
    }
    __syncthreads();

    float g[RAD + 1];
    g[0] = 1.7320508075688773f;
#pragma unroll
    for (int k = 1; k <= RAD; ++k) g[k] = g[k - 1] * (-0.26794919243112270647f);

    float acc[3][4];
#pragma unroll
    for (int c = 0; c < 3; ++c) { acc[c][0] = acc[c][1] = acc[c][2] = acc[c][3] = 0.f; }

#pragma unroll
    for (int c = 0; c < 3; ++c) {
        const float* p = pl + c * PLN + 4 * t;
        float w[40];
#pragma unroll
        for (int i = 0; i < 10; ++i) {
            float4 v = *(const float4*)(p + 4 * i);
            w[4 * i] = v.x; w[4 * i + 1] = v.y; w[4 * i + 2] = v.z; w[4 * i + 3] = v.w;
        }
#pragma unroll
        for (int jq = 0; jq < 4; ++jq) {
#pragma unroll
            for (int k = -RAD; k <= RAD; ++k) {
                acc[c][jq] += g[k < 0 ? -k : k] * w[jq + RAD + k];
            }
        }
    }

    float outv[12];
#pragma unroll
    for (int e = 0; e < 12; ++e) outv[e] = acc[e % 3][e / 3];
    float4 s0, s1, s2;
    s0.x = outv[0]; s0.y = outv[1]; s0.z = outv[2]; s0.w = outv[3];
    s1.x = outv[4]; s1.y = outv[5]; s1.z = outv[6]; s1.w = outv[7];
    s2.x = outv[8]; s2.y = outv[9]; s2.z = outv[10]; s2.w = outv[11];
    *(float4*)(row + 12 * t) = s0;
    *(float4*)(row + 12 * t + 4) = s1;
    *(float4*)(row + 12 * t + 8) = s2;
}

// ---------------- kernel 3: 4x4 cubic gather, batch-amortized ----------------
// grid (1024, NBS): thread owns one (h,w); computes 16 weights + 16 clamped
// tap offsets ONCE (batch-independent), then loops over B_/NBS batches doing
// only 16 dwordx3 loads + 48 FMA + clamp + store per batch.
__global__ __launch_bounds__(256) void k_sample(const float* __restrict__ coef,
                                                const float* __restrict__ dyp,
                                                const float* __restrict__ dxp,
                                                float* __restrict__ out) {
    const int idx = blockIdx.x * 256 + threadIdx.x;   // 0..262143
    const int h = idx >> 10, w = idx & 1023;
    const int b0 = blockIdx.y * (B_ / NBS);

    float cy = (float)h + dyp[idx];
    float cx = (float)w + dxp[idx];
    float byf = floorf(cy), bxf = floorf(cx);
    int by = (int)byf, bx = (int)bxf;
    float wy[4], wx[4];
    cubw(cy - byf, wy);
    cubw(cx - bxf, wx);

    int off[16];
    float wgt[16];
#pragma unroll
    for (int ky = 0; ky < 4; ++ky) {
        int iy = min(max(by + ky - 1, 0), H_ - 1);
#pragma unroll
        for (int kx = 0; kx < 4; ++kx) {
            int ix = min(max(bx + kx - 1, 0), W_ - 1);
            off[ky * 4 + kx] = iy * ROWF + ix * 3;
            wgt[ky * 4 + kx] = wy[ky] * wx[kx];
        }
    }

    const float* cb = coef + (size_t)b0 * (H_ * ROWF);
    float* ob = out + ((size_t)(b0 * H_ + h) * W_ + w) * 3;

#pragma unroll 1
    for (int bb = 0; bb < B_ / NBS; ++bb) {
        float a0 = 0.f, a1 = 0.f, a2 = 0.f;
#pragma unroll
        for (int k = 0; k < 16; ++k) {
            const float* p = cb + off[k];
            float wk = wgt[k];
            a0 = fmaf(wk, p[0], a0);
            a1 = fmaf(wk, p[1], a1);
            a2 = fmaf(wk, p[2], a2);
        }
        ob[0] = clamp01(a0);
        ob[1] = clamp01(a1);
        ob[2] = clamp01(a2);
        cb += (size_t)H_ * ROWF;
        ob += (size_t)H_ * W_ * 3;
    }
}

extern "C" void kernel_launch(void* const* d_in, const int* in_sizes, int n_in,
                              void* d_out, int out_size, void* d_ws, size_t ws_size,
                              hipStream_t stream) {
    const float* x = (const float*)d_in[0];      // [32,256,1024,3]
    const float* disp = (const float*)d_in[1];   // [2,3,3]
    float* out = (float*)d_out;

    char* ws = (char*)d_ws;
    float* coef = (float*)ws;                                  // 96 MiB
    float* dy = (float*)(ws + 100663296ull);                   // 1 MiB
    float* dx = (float*)(ws + 100663296ull + 1048576ull);      // 1 MiB

    k_disp<<<dim3((H_ * W_) / 256), dim3(256), 0, stream>>>(disp, dy, dx);

    dim3 g1(ROWF / 64, B_);
    k_prefilt_h<<<g1, dim3(256), 0, stream>>>(x, coef);

    k_prefilt_w<<<dim3(B_ * H_), dim3(256), 0, stream>>>(coef);

    dim3 g3((H_ * W_) / 256, NBS);
    k_sample<<<g3, dim3(256), 0, stream>>>(coef, dy, dx, out);
}